// Round 6
// baseline (615.427 us; speedup 1.0000x reference)
//
#include <hip/hip_runtime.h>

#define B_ 256
#define L_ 1024
#define T_ 64

typedef float f4v __attribute__((ext_vector_type(4)));

__device__ __forceinline__ float rfl(float x) {
    return __int_as_float(__builtin_amdgcn_readfirstlane(__float_as_int(x)));
}
// Wavefront rotate-by-1 DPP (GFX9-family ctrl: 0x134 = WAVE_ROL1, 0x13C = WAVE_ROR1)
__device__ __forceinline__ int roti(int i) {
    return __builtin_amdgcn_update_dpp(i, i, 0x134, 0xF, 0xF, false);
}
__device__ __forceinline__ int rori(int i) {
    return __builtin_amdgcn_update_dpp(i, i, 0x13C, 0xF, 0xF, false);
}
__device__ __forceinline__ float rotf(float x) {
    return __int_as_float(roti(__float_as_int(x)));
}
__device__ __forceinline__ float rorf(float x) {
    return __int_as_float(rori(__float_as_int(x)));
}

#define REP32(M) M(0) M(1) M(2) M(3) M(4) M(5) M(6) M(7) M(8) M(9) M(10) M(11) \
    M(12) M(13) M(14) M(15) M(16) M(17) M(18) M(19) M(20) M(21) M(22) M(23) \
    M(24) M(25) M(26) M(27) M(28) M(29) M(30) M(31)

// One wave per chain; blockIdx<256: forward batch b; else backward.
// Lane = tag k. E=exp(trans) in 64 NAMED scalar VGPRs (eA0..eA31,eB0..eB31) --
// no arrays anywhere (R5 post-mortem: array -> scratch -> vmcnt-window
// overflow -> per-step drains). Dot via two counter-rotating DPP streams:
// stream A uses offsets +0..+31 (use-then-rol1), stream B offsets -1..-32
// (ror1-then-use); together they tile all 64 columns. Gather indices at init
// are evolved by the SAME DPP ops, so the mapping is self-consistent
// independent of hardware rotation direction. Zero LDS / readlane / in-loop
// vmcnt on the recurrence; only em prefetch loads + the alpha/beta store.
__global__ __launch_bounds__(64, 1)
void crf_scan(const float* __restrict__ em, const float* __restrict__ start_t,
              const float* __restrict__ end_t, const float* __restrict__ trans,
              const int* __restrict__ mask, float* __restrict__ alpha,
              float* __restrict__ beta, float* __restrict__ zbuf)
{
    const int lane = threadIdx.x;
    const int cb = blockIdx.x;
    const bool fwd = cb < B_;
    const int b = fwd ? cb : cb - B_;

#define DECL_E(s) float eA##s, eB##s;
    REP32(DECL_E)
#undef DECL_E

    {
        int idxA = lane;
        int idxB = lane;
        if (fwd) {
            // fwd: lane k needs E[j][k] for j = idx  -> trans[idx*T + lane]
#define GF(s) eA##s = __expf(trans[idxA * T_ + lane]); idxA = roti(idxA); \
              idxB = rori(idxB); eB##s = __expf(trans[idxB * T_ + lane]);
            REP32(GF)
#undef GF
        } else {
            // bwd: lane k needs E[k][j] for j = idx  -> trans[lane*T + idx]
#define GB(s) eA##s = __expf(trans[lane * T_ + idxA]); idxA = roti(idxA); \
              idxB = rori(idxB); eB##s = __expf(trans[lane * T_ + idxB]);
            REP32(GB)
#undef GB
        }
    }
    // discourage rematerialization of the gather+exp into the loop
#define PIN(s) asm volatile("" : "+v"(eA##s), "+v"(eB##s));
    REP32(PIN)
#undef PIN

    const float* emb = em + (size_t)b * (L_ * T_);
    const int* mb = mask + (size_t)b * L_;
    const size_t stride = (size_t)B_ * T_;

    // the 32-substep systolic dot (4 ops/substep, dep chains 4 apart)
#define DOT(s) accA = fmaf(uA, eA##s, accA); uA = rotf(uA); \
               uB = rorf(uB);                accB = fmaf(uB, eB##s, accB);

    if (fwd) {
        float st0 = emb[lane] + start_t[lane];
        float c = rfl(st0);
        float u = __expf(st0 - c);                 // u[0] == 1
        float* ap = alpha + (size_t)b * T_ + lane;
        *ap = st0;
        ap += stride;

        // depth-8 em/mask prefetch (named regs)
        float pe0 = emb[1 * T_ + lane], pe1 = emb[2 * T_ + lane],
              pe2 = emb[3 * T_ + lane], pe3 = emb[4 * T_ + lane],
              pe4 = emb[5 * T_ + lane], pe5 = emb[6 * T_ + lane],
              pe6 = emb[7 * T_ + lane], pe7 = emb[8 * T_ + lane];
        int pm0 = mb[1], pm1 = mb[2], pm2 = mb[3], pm3 = mb[4],
            pm4 = mb[5], pm5 = mb[6], pm6 = mb[7], pm7 = mb[8];

        for (int t = 1; t < L_; ++t) {
            float f = __expf(pe0);
            int mv = pm0;
            pe0 = pe1; pe1 = pe2; pe2 = pe3; pe3 = pe4;
            pe4 = pe5; pe5 = pe6; pe6 = pe7;
            pm0 = pm1; pm1 = pm2; pm2 = pm3; pm3 = pm4;
            pm4 = pm5; pm5 = pm6; pm6 = pm7;
            int tn = t + 8; if (tn > L_ - 1) tn = L_ - 1;
            pe7 = emb[(size_t)tn * T_ + lane];
            pm7 = mb[tn];

            float uA = u, uB = u;
            float accA = 0.f, accB = 0.f;
            REP32(DOT)
            float dot = accA + accB;

            float f0 = rfl(f);
            float d0 = rfl(dot);
            float u00 = d0 * f0;                   // unnormalized new lane0
            float r = __builtin_amdgcn_rcpf(u00);
            float cand = (dot * f) * r;
            float cn = c + __logf(u00);
            float un = (mv != 0) ? cand : u;
            c = (mv != 0) ? cn : c;
            float av = c + __logf(un);             // side chain (store only)
            *ap = av;
            ap += stride;
            u = un;
        }
        // z_b = c + log(sum_k u_k * exp(end_k))
        float v = u * __expf(end_t[lane]);
        for (int off = 32; off; off >>= 1) v += __shfl_xor(v, off);
        if (lane == 0) zbuf[b] = c + __logf(v);
    } else {
        float bv0 = end_t[lane];
        float c = rfl(bv0);
        float u = __expf(bv0 - c);
        float* bp = beta + ((size_t)(L_ - 1) * B_ + b) * T_ + lane;
        *bp = bv0;
        bp -= stride;

        float pe0 = emb[(size_t)(L_ - 1) * T_ + lane], pe1 = emb[(size_t)(L_ - 2) * T_ + lane],
              pe2 = emb[(size_t)(L_ - 3) * T_ + lane], pe3 = emb[(size_t)(L_ - 4) * T_ + lane],
              pe4 = emb[(size_t)(L_ - 5) * T_ + lane], pe5 = emb[(size_t)(L_ - 6) * T_ + lane],
              pe6 = emb[(size_t)(L_ - 7) * T_ + lane], pe7 = emb[(size_t)(L_ - 8) * T_ + lane];
        int pm0 = mb[L_ - 1], pm1 = mb[L_ - 2], pm2 = mb[L_ - 3],
            pm3 = mb[L_ - 4], pm4 = mb[L_ - 5], pm5 = mb[L_ - 6],
            pm6 = mb[L_ - 7], pm7 = mb[L_ - 8];

        for (int i = L_ - 1; i >= 1; --i) {
            float f = __expf(pe0);
            int mv = pm0;
            pe0 = pe1; pe1 = pe2; pe2 = pe3; pe3 = pe4;
            pe4 = pe5; pe5 = pe6; pe6 = pe7;
            pm0 = pm1; pm1 = pm2; pm2 = pm3; pm3 = pm4;
            pm4 = pm5; pm5 = pm6; pm6 = pm7;
            int tn = i - 8; if (tn < 1) tn = 1;
            pe7 = emb[(size_t)tn * T_ + lane];
            pm7 = mb[tn];

            // w_j = u_j * exp(em_j); out_k = sum_j w_j * E[k][j]
            float w = u * f;
            float uA = w, uB = w;
            float accA = 0.f, accB = 0.f;
            REP32(DOT)
            float dot = accA + accB;

            float u00 = rfl(dot);
            float r = __builtin_amdgcn_rcpf(u00);
            float cand = dot * r;
            float cn = c + __logf(u00);
            float un = (mv != 0) ? cand : u;
            c = (mv != 0) ? cn : c;
            float bvv = c + __logf(un);
            *bp = bvv;
            bp -= stride;
            u = un;
        }
    }
#undef DOT
}

// out = exp(alpha + beta - z[b]); beta already resides in d_out.
// Exact-trip grid-stride: 2048 blocks x 256 threads x 8 independent f4 iters.
__global__ __launch_bounds__(256)
void crf_finalize(const float* __restrict__ alpha,
                  const float* __restrict__ zbuf,
                  float* __restrict__ out)
{
    const f4v* a4 = (const f4v*)alpha;
    f4v* o4 = (f4v*)out;
    size_t base = (size_t)blockIdx.x * 256 + threadIdx.x;
    const size_t step = (size_t)2048 * 256;
#pragma unroll
    for (int r = 0; r < 8; ++r) {
        size_t i4 = base + (size_t)r * step;
        int b = (int)((i4 >> 4) & (B_ - 1));       // 16 float4 per (t,b) row
        float z = zbuf[b];
        f4v a = a4[i4];
        f4v bb = o4[i4];
        f4v o;
        o.x = __expf(a.x + bb.x - z);
        o.y = __expf(a.y + bb.y - z);
        o.z = __expf(a.z + bb.z - z);
        o.w = __expf(a.w + bb.w - z);
        __builtin_nontemporal_store(o, &o4[i4]);
    }
}

extern "C" void kernel_launch(void* const* d_in, const int* in_sizes, int n_in,
                              void* d_out, int out_size, void* d_ws, size_t ws_size,
                              hipStream_t stream) {
    const float* em = (const float*)d_in[0];
    const float* st = (const float*)d_in[1];
    const float* en = (const float*)d_in[2];
    const float* tr = (const float*)d_in[3];
    const int*   mk = (const int*)d_in[4];
    float* out   = (float*)d_out;
    float* alpha = (float*)d_ws;
    float* zbuf  = alpha + (size_t)L_ * B_ * T_;

    crf_scan<<<2 * B_, T_, 0, stream>>>(em, st, en, tr, mk, alpha, out, zbuf);
    crf_finalize<<<2048, 256, 0, stream>>>(alpha, zbuf, out);
}